// Round 23
// baseline (231.270 us; speedup 1.0000x reference)
//
#include <hip/hip_runtime.h>
#include <hip/hip_bf16.h>
#include <hip/hip_cooperative_groups.h>

namespace cg = cooperative_groups;

#define B_ 2
#define P_ 100000
#define CIN_ 23
#define C_ 64
#define H_ 512
#define W_ 512
#define S_ (H_*W_)       // 262144
#define NPT_ (B_*P_)     // 200000
#define NVOX_ (B_*S_)    // 524288

typedef __attribute__((ext_vector_type(8))) short short8;
typedef __attribute__((ext_vector_type(4))) float f32x4;
typedef __attribute__((ext_vector_type(4))) int i32x4;
// 4B-aligned vectors (feat rows 92B -> dword-aligned only)
typedef __attribute__((ext_vector_type(4), aligned(4))) float f32x4u;

__device__ inline unsigned short f2bf(float f) {
    union { __hip_bfloat16 h; unsigned short u; } cv;
    cv.h = __float2bfloat16(f);
    return cv.u;
}
__device__ inline float bf2f(unsigned short u) {
    union { unsigned int i; float f; } cv;
    cv.i = ((unsigned int)u) << 16;
    return cv.f;
}
// expand packed 2xbf16 word -> two floats (1 VALU op each)
__device__ inline void bf2x(unsigned int u, float& lo, float& hi) {
    union { unsigned int i; float f; } a, b;
    a.i = u << 16;
    b.i = u & 0xffff0000u;
    lo = a.f; hi = b.f;
}

// ---------------- Stage 1 (cooperative, 513 blocks): clear -> hist -> scan+prep -> ptid
__global__ __launch_bounds__(256) void k_front(
    const int* __restrict__ indices,
    const int* __restrict__ paddings,
    int* __restrict__ cnt,
    int* __restrict__ rank,
    int* __restrict__ cur,
    int* __restrict__ rid,
    int* __restrict__ off_c,
    int* __restrict__ cnt_c,
    int* __restrict__ gcursor,          // [0]=point cursor [1]=row cursor
    int* __restrict__ ptid,
    const float* __restrict__ conv_w,
    const float* __restrict__ w_pn,
    const float* __restrict__ g1, const float* __restrict__ b1,
    const float* __restrict__ m1, const float* __restrict__ v1,
    const float* __restrict__ g2, const float* __restrict__ b2,
    const float* __restrict__ m2, const float* __restrict__ v2,
    unsigned short* __restrict__ cwb,   // [8][64][8] bf16 conv-W fragments
    unsigned short* __restrict__ wpb,   // [4][64][8] bf16 (w_pn * s1) fragments
    float* __restrict__ o1v,
    float* __restrict__ scv, float* __restrict__ shv)
{
    cg::grid_group grid = cg::this_grid();
    int tid = threadIdx.x;
    int bid = blockIdx.x;
    int gt  = bid * 256 + tid;

    // ---- phase 0: clear cnt (2MB) + gcursor (16B) ----
    {
        int i = gt * 4;
        if (i <= NVOX_)                          // i == NVOX_ covers gcursor[0..3]
            *(i32x4*)(cnt + i) = (i32x4){0, 0, 0, 0};
    }
    grid.sync();

    // ---- phase 1: histogram, 4 points/thread; record per-point rank ----
    {
        int t4 = gt * 4;
        if (t4 < NPT_) {                         // NPT_ % 4 == 0
            i32x4 idx4 = *(const i32x4*)(indices + t4);
            i32x4 pad4 = *(const i32x4*)(paddings + t4);
            int vb = (t4 >= P_) ? S_ : 0;        // P_ % 4 == 0 -> same batch for all 4
            #pragma unroll
            for (int j = 0; j < 4; ++j)
                if (pad4[j] == 0)
                    rank[t4 + j] = atomicAdd(&cnt[vb + idx4[j]], 1);
        }
    }
    grid.sync();

    // ---- phase 2: dual exclusive scan (blocks 0..511) + param prep (block 512) ----
    if (bid >= 512) {
        int t = tid;
        if (t < 64) {
            float s = g1[t] * rsqrtf(v1[t] + 1e-5f);
            o1v[t] = b1[t] - m1[t] * s;
            float s2 = g2[t] * rsqrtf(v2[t] + 1e-3f);
            scv[t] = s2;
            shv[t] = b2[t] - m2[t] * s2;
        }
        #pragma unroll
        for (int e = 0; e < 16; ++e) {
            int idx  = t * 16 + e;              // 0..4095
            int f    = idx >> 9;                // 0..7
            int lane = (idx >> 3) & 63;
            int j    = idx & 7;
            int tq = f >> 1, ks = f & 1;
            int row = lane & 15, grp = lane >> 4;
            cwb[idx] = f2bf(conv_w[(tq * 16 + row) * 64 + ks * 32 + grp * 8 + j]);
        }
        #pragma unroll
        for (int e = 0; e < 8; ++e) {
            int idx  = t * 8 + e;               // 0..2047
            int tq   = idx >> 9;                // 0..3
            int lane = (idx >> 3) & 63;
            int j    = idx & 7;
            int row = lane & 15, grp = lane >> 4;
            int n = tq * 16 + row;
            int k = grp * 8 + j;
            // fold BN1 scale (s1[n] > 0): max(z*s1) == max(z)*s1
            float s1n = g1[n] * rsqrtf(v1[n] + 1e-5f);
            wpb[idx] = (k < CIN_) ? f2bf(w_pn[k * C_ + n] * s1n) : 0;
        }
    } else {
        __shared__ int lds_c[256], lds_o[256];
        __shared__ int sbase_c, sbase_o;
        int base = bid * 1024 + tid * 4;
        i32x4 c = *(const i32x4*)(cnt + base);
        int o0 = c[0] > 0, o1 = c[1] > 0, o2 = c[2] > 0, o3 = c[3] > 0;
        int sc1 = c[0] + c[1], sc2 = sc1 + c[2], sc3 = sc2 + c[3];
        int so1 = o0 + o1,     so2 = so1 + o2,   so3 = so2 + o3;
        lds_c[tid] = sc3;
        lds_o[tid] = so3;
        __syncthreads();
        #pragma unroll
        for (int d = 1; d < 256; d <<= 1) {
            int vc = (tid >= d) ? lds_c[tid - d] : 0;
            int vo = (tid >= d) ? lds_o[tid - d] : 0;
            __syncthreads();
            if (tid >= d) { lds_c[tid] += vc; lds_o[tid] += vo; }
            __syncthreads();
        }
        if (tid == 0) {
            sbase_c = atomicAdd(&gcursor[0], lds_c[255]);
            sbase_o = atomicAdd(&gcursor[1], lds_o[255]);
        }
        __syncthreads();
        int oc = sbase_c + (tid == 0 ? 0 : lds_c[tid - 1]);
        int oo = sbase_o + (tid == 0 ? 0 : lds_o[tid - 1]);
        i32x4 e, ridv;
        e[0] = oc; e[1] = oc + c[0]; e[2] = oc + sc1; e[3] = oc + sc2;
        ridv[0] = o0 ? oo            : -1;
        ridv[1] = o1 ? oo + so1 - o1 : -1;
        ridv[2] = o2 ? oo + so2 - o2 : -1;
        ridv[3] = o3 ? oo + so3 - o3 : -1;
        *(i32x4*)(cur + base) = e;
        *(i32x4*)(rid + base) = ridv;
        #pragma unroll
        for (int i = 0; i < 4; ++i) {
            if (ridv[i] >= 0) {
                off_c[ridv[i]] = e[i];
                cnt_c[ridv[i]] = c[i];
            }
        }
    }
    grid.sync();

    // ---- phase 3: atomic-free ptid scatter (slot = base + rank), 2 pts/thread ----
    {
        int p0 = gt * 2;
        #pragma unroll
        for (int j = 0; j < 2; ++j) {
            int pt = p0 + j;
            if (pt < NPT_ && paddings[pt] == 0) {
                int v = ((pt >= P_) ? S_ : 0) + indices[pt];
                ptid[cur[v] + rank[pt]] = pt;
            }
        }
    }
}

// ---------------- Stage 2: FUSED PointNet-GEMM + max + BN1 + ReLU + conv + BN2 + ReLU
// one wave = 16 occupied rows (identical to R22 best)
__global__ __launch_bounds__(256) void k_redconv(
    const float* __restrict__ feat,
    const int* __restrict__ ptid,
    const int* __restrict__ off_c,
    const int* __restrict__ cnt_c,
    const int* __restrict__ gcursor,          // [1] = nocc
    const unsigned short* __restrict__ wpb,   // [4][64][8] (w_pn * s1)
    const float* __restrict__ o1v,
    const unsigned short* __restrict__ cwb,   // [8][64][8]
    const float* __restrict__ scv, const float* __restrict__ shv,
    unsigned short* __restrict__ grid_c)      // bf16 [nocc][C_] compact
{
    __shared__ unsigned short lds[4][16][64];   // per-wave 16x64 bf16 tile (8KB)

    int lane = threadIdx.x & 63;
    int wv   = threadIdx.x >> 6;
    int wid  = (blockIdx.x * 256 + threadIdx.x) >> 6;
    int r0   = wid * 16;
    int nocc = gcursor[1];
    if (r0 >= nocc) return;

    int col = lane & 15;
    int grp = lane >> 4;

    int rA    = r0 + col;
    bool livA = rA < nocc;
    int ciA   = livA ? cnt_c[rA] : 0;
    int oiA   = livA ? off_c[rA] : 0;

    int ci4[4];
    #pragma unroll
    for (int r = 0; r < 4; ++r) ci4[r] = __shfl(ciA, grp * 4 + r);

    short8 bz[4];
    #pragma unroll
    for (int t = 0; t < 4; ++t)
        bz[t] = *(const short8*)(wpb + ((size_t)t * 64 + lane) * 8);

    f32x4 mx[4];
    #pragma unroll
    for (int t = 0; t < 4; ++t) mx[t] = (f32x4){-1e30f, -1e30f, -1e30f, -1e30f};

    for (int j = 0; ; ++j) {
        if (!__any(j < ciA)) break;
        int jj = j < ciA ? j : 0;
        int pt = ptid[oiA + jj];
        const float* f = feat + (size_t)pt * CIN_;
        short8 a = (short8){0,0,0,0,0,0,0,0};
        if (grp < 3) {
            f32x4u v0 = *(const f32x4u*)(f + grp * 8);
            f32x4u v1 = *(const f32x4u*)(f + grp * 8 + 4);
            #pragma unroll
            for (int jx = 0; jx < 4; ++jx) {
                int k0 = grp * 8 + jx;
                int k1 = k0 + 4;
                a[jx]     = (short)(k0 < CIN_ ? f2bf(v0[jx]) : 0);
                a[jx + 4] = (short)(k1 < CIN_ ? f2bf(v1[jx]) : 0);
            }
        }
        #pragma unroll
        for (int t = 0; t < 4; ++t) {
            f32x4 zt = __builtin_amdgcn_mfma_f32_16x16x32_bf16(
                a, bz[t], (f32x4){0.f, 0.f, 0.f, 0.f}, 0, 0, 0);
            #pragma unroll
            for (int r = 0; r < 4; ++r)
                if (j < ci4[r]) mx[t][r] = fmaxf(mx[t][r], zt[r]);
        }
    }

    #pragma unroll
    for (int t = 0; t < 4; ++t) {
        float o1 = o1v[t * 16 + col];
        #pragma unroll
        for (int r = 0; r < 4; ++r) {
            int row = grp * 4 + r;
            float val = fmaxf(mx[t][r] + o1, 0.f);
            lds[wv][row][(t * 16 + col) ^ ((row & 7) << 3)] = f2bf(val);
        }
    }
    // wave-private tile: ds_read-after-ds_write ordered by lgkmcnt

    short8 a2[2];
    #pragma unroll
    for (int ks = 0; ks < 2; ++ks)
        a2[ks] = *(const short8*)&lds[wv][col][(ks * 32 + grp * 8) ^ ((col & 7) << 3)];

    short8 bfrag[4][2];
    #pragma unroll
    for (int t = 0; t < 4; ++t)
        #pragma unroll
        for (int ks = 0; ks < 2; ++ks)
            bfrag[t][ks] = *(const short8*)(cwb + ((size_t)(t * 2 + ks) * 64 + lane) * 8);

    f32x4 acc[4];
    #pragma unroll
    for (int t = 0; t < 4; ++t) acc[t] = (f32x4){0.f, 0.f, 0.f, 0.f};
    #pragma unroll
    for (int t = 0; t < 4; ++t) {
        acc[t] = __builtin_amdgcn_mfma_f32_16x16x32_bf16(a2[0], bfrag[t][0], acc[t], 0, 0, 0);
        acc[t] = __builtin_amdgcn_mfma_f32_16x16x32_bf16(a2[1], bfrag[t][1], acc[t], 0, 0, 0);
    }

    float sc[4], sh[4];
    #pragma unroll
    for (int t = 0; t < 4; ++t) {
        int n = t * 16 + col;
        sc[t] = scv[n];
        sh[t] = shv[n];
    }
    #pragma unroll
    for (int rq = 0; rq < 4; ++rq) {
        int rr = r0 + grp * 4 + rq;
        if (rr < nocc) {
            unsigned short* op = grid_c + (size_t)rr * C_;
            #pragma unroll
            for (int t = 0; t < 4; ++t) {
                float val = fmaxf(acc[t][rq] * sc[t] + sh[t], 0.f);
                op[t * 16 + col] = f2bf(val);
            }
        }
    }
}

// ---------------- Stage 3: bilinear gather, 32 pts/wave, compact rows via rid --------
__global__ __launch_bounds__(256) void k_gather32(
    const unsigned short* __restrict__ grid_c,  // bf16 compact rows
    const int* __restrict__ rid,
    const float* __restrict__ vxyz,
    const float* __restrict__ shv,
    float* __restrict__ out)                    // f32 output
{
    int lane = threadIdx.x & 63;
    int q    = lane >> 4;                       // point-within-quad
    int ch   = (lane & 15) * 4;                 // 4 channels per lane
    int gw   = (blockIdx.x * 256 + threadIdx.x) >> 6;
    int p0   = gw * 32;
    if (p0 >= NPT_) return;                     // NPT_ % 32 == 0

    f32x4 cstv = *(const f32x4*)(shv + ch);
    #pragma unroll
    for (int j = 0; j < 4; ++j) cstv[j] = fmaxf(cstv[j], 0.f);

    const unsigned short* gc = grid_c + ch;

    #pragma unroll
    for (int it = 0; it < 8; ++it) {
        int pt = p0 + it * 4 + q;
        int b  = (pt >= P_);                    // B_ == 2
        float xq = vxyz[(size_t)pt * 3 + 0];
        float yq = vxyz[(size_t)pt * 3 + 1];
        int x0 = (int)floorf(xq); x0 = min(max(x0, 0), W_ - 1);
        int x1 = min(x0 + 1, W_ - 1);
        int y0 = (int)floorf(yq); y0 = min(max(y0, 0), H_ - 1);
        int y1 = min(y0 + 1, H_ - 1);
        float x0f = (float)x0, x1f = (float)x1, y0f = (float)y0, y1f = (float)y1;
        float wa = (x1f - xq) * (y1f - yq);
        float wb = (x1f - xq) * (yq - y0f);
        float wc = (xq - x0f) * (y1f - yq);
        float wd = (xq - x0f) * (yq - y0f);

        int ia = y0 * W_ + x0, ib = y1 * W_ + x0, ic = y0 * W_ + x1, id = y1 * W_ + x1;
        const int* rb = rid + (size_t)b * S_;

        int ra = rb[ia], rbn = rb[ib], rc = rb[ic], rd = rb[id];
        uint2 Ra = *(const uint2*)(gc + (size_t)max(ra,  0) * C_);
        uint2 Rb = *(const uint2*)(gc + (size_t)max(rbn, 0) * C_);
        uint2 Rc = *(const uint2*)(gc + (size_t)max(rc,  0) * C_);
        uint2 Rd = *(const uint2*)(gc + (size_t)max(rd,  0) * C_);

        float A0,A1,A2,A3, B0,B1,B2,B3, C0,C1,C2,C3, D0,D1,D2,D3;
        bf2x(Ra.x, A0, A1); bf2x(Ra.y, A2, A3);
        bf2x(Rb.x, B0, B1); bf2x(Rb.y, B2, B3);
        bf2x(Rc.x, C0, C1); bf2x(Rc.y, C2, C3);
        bf2x(Rd.x, D0, D1); bf2x(Rd.y, D2, D3);

        bool oa = ra >= 0, ob = rbn >= 0, oc = rc >= 0, od = rd >= 0;
        f32x4 res;
        res[0] = wa * (oa ? A0 : cstv[0]) + wb * (ob ? B0 : cstv[0])
               + wc * (oc ? C0 : cstv[0]) + wd * (od ? D0 : cstv[0]);
        res[1] = wa * (oa ? A1 : cstv[1]) + wb * (ob ? B1 : cstv[1])
               + wc * (oc ? C1 : cstv[1]) + wd * (od ? D1 : cstv[1]);
        res[2] = wa * (oa ? A2 : cstv[2]) + wb * (ob ? B2 : cstv[2])
               + wc * (oc ? C2 : cstv[2]) + wd * (od ? D2 : cstv[2]);
        res[3] = wa * (oa ? A3 : cstv[3]) + wb * (ob ? B3 : cstv[3])
               + wc * (oc ? C3 : cstv[3]) + wd * (od ? D3 : cstv[3]);

        *(f32x4*)(out + (size_t)pt * C_ + ch) = res;
    }
}

extern "C" void kernel_launch(void* const* d_in, const int* in_sizes, int n_in,
                              void* d_out, int out_size, void* d_ws, size_t ws_size,
                              hipStream_t stream)
{
    const float* feat     = (const float*)d_in[1];
    const int*   indices  = (const int*)d_in[3];
    const int*   paddings = (const int*)d_in[4];
    const float* vxyz     = (const float*)d_in[5];
    const float* w_pn     = (const float*)d_in[6];
    const float* g1       = (const float*)d_in[7];
    const float* b1       = (const float*)d_in[8];
    const float* m1       = (const float*)d_in[9];
    const float* v1       = (const float*)d_in[10];
    const float* cw       = (const float*)d_in[11];
    const float* g2       = (const float*)d_in[12];
    const float* b2       = (const float*)d_in[13];
    const float* m2       = (const float*)d_in[14];
    const float* v2       = (const float*)d_in[15];

    // ws layout: grid_c 25.6MB | cnt 2MB | gcursor 16B | cur 2MB | rid 2MB |
    //            off_c 0.8MB | cnt_c 0.8MB | ptid 0.8MB | rank 0.8MB |
    //            cwb 8KB | wpb 4KB | o1v/scv/shv 3x256B
    char* p = (char*)d_ws;
    unsigned short* grid_c = (unsigned short*)p;  p += (size_t)NPT_ * C_ * 2;
    int* cnt   = (int*)p;  p += (size_t)NVOX_ * 4;
    int* gcur  = (int*)p;  p += 16;
    int* cur   = (int*)p;  p += (size_t)NVOX_ * 4;
    int* rid   = (int*)p;  p += (size_t)NVOX_ * 4;
    int* off_c = (int*)p;  p += (size_t)NPT_ * 4;
    int* cnt_c = (int*)p;  p += (size_t)NPT_ * 4;
    int* ptid  = (int*)p;  p += (size_t)NPT_ * 4;
    int* rank  = (int*)p;  p += (size_t)NPT_ * 4;
    unsigned short* cwb = (unsigned short*)p;  p += 8 * 64 * 8 * 2;
    unsigned short* wpb = (unsigned short*)p;  p += 4 * 64 * 8 * 2;
    float* o1v = (float*)p;  p += 64 * 4;
    float* scv = (float*)p;  p += 64 * 4;
    float* shv = (float*)p;

    // cooperative front-end: clear -> hist -> scan+prep -> ptid (1 dispatch, 513 blocks)
    void* args[] = {
        (void*)&indices, (void*)&paddings, (void*)&cnt, (void*)&rank,
        (void*)&cur, (void*)&rid, (void*)&off_c, (void*)&cnt_c, (void*)&gcur,
        (void*)&ptid,
        (void*)&cw, (void*)&w_pn, (void*)&g1, (void*)&b1, (void*)&m1, (void*)&v1,
        (void*)&g2, (void*)&b2, (void*)&m2, (void*)&v2,
        (void*)&cwb, (void*)&wpb, (void*)&o1v, (void*)&scv, (void*)&shv
    };
    hipLaunchCooperativeKernel((void*)k_front, dim3(513), dim3(256), args, 0, stream);

    // nocc <= NPT_: 12500 waves -> 3125 blocks; waves early-out past nocc
    k_redconv<<<3125, 256, 0, stream>>>(feat, ptid, off_c, cnt_c, gcur,
        wpb, o1v, cwb, scv, shv, grid_c);

    // NPT_/32 = 6250 waves -> 1563 blocks
    k_gather32<<<1563, 256, 0, stream>>>(grid_c, rid, vxyz, shv, (float*)d_out);
}

// Round 24
// 76.105 us; speedup vs baseline: 3.0389x; 3.0389x over previous
//
#include <hip/hip_runtime.h>
#include <hip/hip_bf16.h>

#define B_ 2
#define P_ 100000
#define CIN_ 23
#define C_ 64
#define H_ 512
#define W_ 512
#define S_ (H_*W_)       // 262144
#define NPT_ (B_*P_)     // 200000
#define NVOX_ (B_*S_)    // 524288

typedef __attribute__((ext_vector_type(8))) short short8;
typedef __attribute__((ext_vector_type(4))) float f32x4;
typedef __attribute__((ext_vector_type(4))) int i32x4;
// 4B-aligned vectors (feat rows 92B -> dword-aligned only)
typedef __attribute__((ext_vector_type(4), aligned(4))) float f32x4u;

__device__ inline unsigned short f2bf(float f) {
    union { __hip_bfloat16 h; unsigned short u; } cv;
    cv.h = __float2bfloat16(f);
    return cv.u;
}
__device__ inline float bf2f(unsigned short u) {
    union { unsigned int i; float f; } cv;
    cv.i = ((unsigned int)u) << 16;
    return cv.f;
}
// expand packed 2xbf16 word -> two floats (1 VALU op each)
__device__ inline void bf2x(unsigned int u, float& lo, float& hi) {
    union { unsigned int i; float f; } a, b;
    a.i = u << 16;
    b.i = u & 0xffff0000u;
    lo = a.f; hi = b.f;
}

// ---------------- Stage 0: clear cnt (2MB) + gcursor (16B) ----------------
__global__ __launch_bounds__(256) void k_clear(int* __restrict__ cnt)
{
    int i = (blockIdx.x * 256 + threadIdx.x) * 4;
    if (i > NVOX_) return;                    // i == NVOX_ covers gcursor[0..3]
    *(i32x4*)(cnt + i) = (i32x4){0, 0, 0, 0};
}

// ---------------- Stage 1: histogram, 4 points/thread; record per-point rank --------
__global__ __launch_bounds__(256) void k_hist(
    const int* __restrict__ indices,
    const int* __restrict__ paddings,
    int* __restrict__ cnt,
    int* __restrict__ rank)                    // within-voxel rank per point
{
    int t4 = (blockIdx.x * 256 + threadIdx.x) * 4;
    if (t4 >= NPT_) return;                    // NPT_ % 4 == 0
    i32x4 idx4 = *(const i32x4*)(indices + t4);
    i32x4 pad4 = *(const i32x4*)(paddings + t4);
    int vb = (t4 / P_) * S_;                   // P_ % 4 == 0 -> same batch for all 4
    #pragma unroll
    for (int j = 0; j < 4; ++j)
        if (pad4[j] == 0)
            rank[t4 + j] = atomicAdd(&cnt[vb + idx4[j]], 1);
}

// ---------------- Stage 2: DUAL exclusive scan (point-slots + occupied-row ids)
//                  + compact segment table (off_c/cnt_c) + (block 512) param prep ----
__global__ __launch_bounds__(256) void k_offsets(
    const int* __restrict__ cnt,
    int* __restrict__ cur,              // segment base per voxel (read-only later)
    int* __restrict__ rid,              // compact row id, -1 if empty
    int* __restrict__ off_c,            // per compact row: segment start
    int* __restrict__ cnt_c,            // per compact row: segment count
    int* __restrict__ gcursor,          // [0]=point cursor [1]=row cursor
    const float* __restrict__ conv_w,
    const float* __restrict__ w_pn,
    const float* __restrict__ g1, const float* __restrict__ b1,
    const float* __restrict__ m1, const float* __restrict__ v1,
    const float* __restrict__ g2, const float* __restrict__ b2,
    const float* __restrict__ m2, const float* __restrict__ v2,
    unsigned short* __restrict__ cwb,   // [8][64][8] bf16 conv-W fragments
    unsigned short* __restrict__ wpb,   // [4][64][8] bf16 (w_pn * s1) fragments
    float* __restrict__ o1v,
    float* __restrict__ scv, float* __restrict__ shv)
{
    if (blockIdx.x >= 512) {            // ---- prep block ----
        int t = threadIdx.x;
        if (t < 64) {
            float s = g1[t] * rsqrtf(v1[t] + 1e-5f);
            o1v[t] = b1[t] - m1[t] * s;
            float s2 = g2[t] * rsqrtf(v2[t] + 1e-3f);
            scv[t] = s2;
            shv[t] = b2[t] - m2[t] * s2;
        }
        #pragma unroll
        for (int e = 0; e < 16; ++e) {
            int idx  = t * 16 + e;              // 0..4095
            int f    = idx >> 9;                // 0..7
            int lane = (idx >> 3) & 63;
            int j    = idx & 7;
            int tq = f >> 1, ks = f & 1;
            int row = lane & 15, grp = lane >> 4;
            cwb[idx] = f2bf(conv_w[(tq * 16 + row) * 64 + ks * 32 + grp * 8 + j]);
        }
        #pragma unroll
        for (int e = 0; e < 8; ++e) {
            int idx  = t * 8 + e;               // 0..2047
            int tq   = idx >> 9;                // 0..3
            int lane = (idx >> 3) & 63;
            int j    = idx & 7;
            int row = lane & 15, grp = lane >> 4;
            int n = tq * 16 + row;
            int k = grp * 8 + j;
            // fold BN1 scale (s1[n] > 0): max(z*s1) == max(z)*s1
            float s1n = g1[n] * rsqrtf(v1[n] + 1e-5f);
            wpb[idx] = (k < CIN_) ? f2bf(w_pn[k * C_ + n] * s1n) : 0;
        }
        return;
    }

    __shared__ int lds_c[256], lds_o[256];
    __shared__ int sbase_c, sbase_o;
    int tid  = threadIdx.x;
    int base = blockIdx.x * 1024 + tid * 4;
    i32x4 c = *(const i32x4*)(cnt + base);
    int o0 = c[0] > 0, o1 = c[1] > 0, o2 = c[2] > 0, o3 = c[3] > 0;
    int sc1 = c[0] + c[1], sc2 = sc1 + c[2], sc3 = sc2 + c[3];
    int so1 = o0 + o1,     so2 = so1 + o2,   so3 = so2 + o3;
    lds_c[tid] = sc3;
    lds_o[tid] = so3;
    __syncthreads();
    #pragma unroll
    for (int d = 1; d < 256; d <<= 1) {
        int vc = (tid >= d) ? lds_c[tid - d] : 0;
        int vo = (tid >= d) ? lds_o[tid - d] : 0;
        __syncthreads();
        if (tid >= d) { lds_c[tid] += vc; lds_o[tid] += vo; }
        __syncthreads();
    }
    if (tid == 0) {
        sbase_c = atomicAdd(&gcursor[0], lds_c[255]);
        sbase_o = atomicAdd(&gcursor[1], lds_o[255]);
    }
    __syncthreads();
    int oc = sbase_c + (tid == 0 ? 0 : lds_c[tid - 1]);
    int oo = sbase_o + (tid == 0 ? 0 : lds_o[tid - 1]);
    i32x4 e, ridv;
    e[0] = oc; e[1] = oc + c[0]; e[2] = oc + sc1; e[3] = oc + sc2;
    ridv[0] = o0 ? oo            : -1;
    ridv[1] = o1 ? oo + so1 - o1 : -1;
    ridv[2] = o2 ? oo + so2 - o2 : -1;
    ridv[3] = o3 ? oo + so3 - o3 : -1;
    *(i32x4*)(cur + base) = e;
    *(i32x4*)(rid + base) = ridv;
    // compact segment table: per occupied row, its (start, count)
    #pragma unroll
    for (int i = 0; i < 4; ++i) {
        if (ridv[i] >= 0) {
            off_c[ridv[i]] = e[i];
            cnt_c[ridv[i]] = c[i];
        }
    }
}

// ---------------- Stage 3: scatter point ids, ATOMIC-FREE (slot = base + rank) ------
__global__ __launch_bounds__(256) void k_ptid(
    const int* __restrict__ indices,
    const int* __restrict__ paddings,
    const int* __restrict__ cur,        // segment base per voxel
    const int* __restrict__ rank,       // within-voxel rank per point
    int* __restrict__ ptid)
{
    int pt = blockIdx.x * 256 + threadIdx.x;
    if (pt >= NPT_) return;
    if (paddings[pt] != 0) return;
    int v = (pt / P_) * S_ + indices[pt];
    ptid[cur[v] + rank[pt]] = pt;
}

// ---------------- Stage 4: FUSED PointNet-GEMM + max + BN1 + ReLU + conv + BN2 + ReLU
// one wave = 16 occupied rows. Per segment element j: load 16 feat rows (A-frag),
// z-tile = mfma(a, wpb, 0), masked fmax in C-layout. Then BN1+ReLU, swizzled-LDS
// transpose (wave-private, no barrier), conv MFMA, BN2+ReLU, contiguous store.
__global__ __launch_bounds__(256) void k_redconv(
    const float* __restrict__ feat,
    const int* __restrict__ ptid,
    const int* __restrict__ off_c,
    const int* __restrict__ cnt_c,
    const int* __restrict__ gcursor,          // [1] = nocc
    const unsigned short* __restrict__ wpb,   // [4][64][8] (w_pn * s1)
    const float* __restrict__ o1v,
    const unsigned short* __restrict__ cwb,   // [8][64][8]
    const float* __restrict__ scv, const float* __restrict__ shv,
    unsigned short* __restrict__ grid_c)      // bf16 [nocc][C_] compact
{
    __shared__ unsigned short lds[4][16][64];   // per-wave 16x64 bf16 tile (8KB)

    int lane = threadIdx.x & 63;
    int wv   = threadIdx.x >> 6;
    int wid  = (blockIdx.x * 256 + threadIdx.x) >> 6;
    int r0   = wid * 16;
    int nocc = gcursor[1];
    if (r0 >= nocc) return;

    int col = lane & 15;        // A-row index within tile / C-col (channel low bits)
    int grp = lane >> 4;        // A k-group / C row-quad

    // A-side segment info for row r0+col (compact rows always have cnt >= 1)
    int rA    = r0 + col;
    bool livA = rA < nocc;
    int ciA   = livA ? cnt_c[rA] : 0;
    int oiA   = livA ? off_c[rA] : 0;

    // C-side counts for rows grp*4+r
    int ci4[4];
    #pragma unroll
    for (int r = 0; r < 4; ++r) ci4[r] = __shfl(ciA, grp * 4 + r);

    // B fragments for the PointNet GEMM (w_pn * s1, zero-padded k>=23)
    short8 bz[4];
    #pragma unroll
    for (int t = 0; t < 4; ++t)
        bz[t] = *(const short8*)(wpb + ((size_t)t * 64 + lane) * 8);

    // running max in C-layout: mx[t][r] = max z[row grp*4+r][ch t*16+col]
    f32x4 mx[4];
    #pragma unroll
    for (int t = 0; t < 4; ++t) mx[t] = (f32x4){-1e30f, -1e30f, -1e30f, -1e30f};

    for (int j = 0; ; ++j) {
        if (!__any(j < ciA)) break;
        int jj = j < ciA ? j : 0;
        int pt = ptid[oiA + jj];
        const float* f = feat + (size_t)pt * CIN_;
        short8 a = (short8){0,0,0,0,0,0,0,0};
        if (grp < 3) {
            f32x4u v0 = *(const f32x4u*)(f + grp * 8);
            f32x4u v1 = *(const f32x4u*)(f + grp * 8 + 4);
            #pragma unroll
            for (int jx = 0; jx < 4; ++jx) {
                int k0 = grp * 8 + jx;
                int k1 = k0 + 4;
                a[jx]     = (short)(k0 < CIN_ ? f2bf(v0[jx]) : 0);
                a[jx + 4] = (short)(k1 < CIN_ ? f2bf(v1[jx]) : 0);
            }
        }
        #pragma unroll
        for (int t = 0; t < 4; ++t) {
            f32x4 zt = __builtin_amdgcn_mfma_f32_16x16x32_bf16(
                a, bz[t], (f32x4){0.f, 0.f, 0.f, 0.f}, 0, 0, 0);
            #pragma unroll
            for (int r = 0; r < 4; ++r)
                if (j < ci4[r]) mx[t][r] = fmaxf(mx[t][r], zt[r]);
        }
    }

    // BN1 offset + ReLU (dead rows: -1e30 -> 0), write transposed swizzled LDS
    #pragma unroll
    for (int t = 0; t < 4; ++t) {
        float o1 = o1v[t * 16 + col];
        #pragma unroll
        for (int r = 0; r < 4; ++r) {
            int row = grp * 4 + r;
            float val = fmaxf(mx[t][r] + o1, 0.f);
            lds[wv][row][(t * 16 + col) ^ ((row & 7) << 3)] = f2bf(val);
        }
    }
    // wave-private tile: ds_read-after-ds_write dependency enforced by lgkmcnt

    // A fragments for conv from swizzled LDS (8-short chunks stay contiguous)
    short8 a2[2];
    #pragma unroll
    for (int ks = 0; ks < 2; ++ks)
        a2[ks] = *(const short8*)&lds[wv][col][(ks * 32 + grp * 8) ^ ((col & 7) << 3)];

    short8 bfrag[4][2];
    #pragma unroll
    for (int t = 0; t < 4; ++t)
        #pragma unroll
        for (int ks = 0; ks < 2; ++ks)
            bfrag[t][ks] = *(const short8*)(cwb + ((size_t)(t * 2 + ks) * 64 + lane) * 8);

    f32x4 acc[4];
    #pragma unroll
    for (int t = 0; t < 4; ++t) acc[t] = (f32x4){0.f, 0.f, 0.f, 0.f};
    #pragma unroll
    for (int t = 0; t < 4; ++t) {
        acc[t] = __builtin_amdgcn_mfma_f32_16x16x32_bf16(a2[0], bfrag[t][0], acc[t], 0, 0, 0);
        acc[t] = __builtin_amdgcn_mfma_f32_16x16x32_bf16(a2[1], bfrag[t][1], acc[t], 0, 0, 0);
    }

    float sc[4], sh[4];
    #pragma unroll
    for (int t = 0; t < 4; ++t) {
        int n = t * 16 + col;
        sc[t] = scv[n];
        sh[t] = shv[n];
    }
    // store: C[mr = grp*4+rq][n = t*16+col] -> grid_c[r0+mr]
    #pragma unroll
    for (int rq = 0; rq < 4; ++rq) {
        int rr = r0 + grp * 4 + rq;
        if (rr < nocc) {
            unsigned short* op = grid_c + (size_t)rr * C_;
            #pragma unroll
            for (int t = 0; t < 4; ++t) {
                float val = fmaxf(acc[t][rq] * sc[t] + sh[t], 0.f);
                op[t * 16 + col] = f2bf(val);
            }
        }
    }
}

// ---------------- Stage 5: bilinear gather, 32 pts/wave, compact rows via rid --------
__global__ __launch_bounds__(256) void k_gather32(
    const unsigned short* __restrict__ grid_c,  // bf16 compact rows
    const int* __restrict__ rid,
    const float* __restrict__ vxyz,
    const float* __restrict__ shv,
    float* __restrict__ out)                    // f32 output
{
    int lane = threadIdx.x & 63;
    int q    = lane >> 4;                       // point-within-quad
    int ch   = (lane & 15) * 4;                 // 4 channels per lane
    int gw   = (blockIdx.x * 256 + threadIdx.x) >> 6;
    int p0   = gw * 32;
    if (p0 >= NPT_) return;                     // NPT_ % 32 == 0

    f32x4 cstv = *(const f32x4*)(shv + ch);
    #pragma unroll
    for (int j = 0; j < 4; ++j) cstv[j] = fmaxf(cstv[j], 0.f);

    const unsigned short* gc = grid_c + ch;

    #pragma unroll
    for (int it = 0; it < 8; ++it) {
        int pt = p0 + it * 4 + q;
        int b  = pt / P_;
        float xq = vxyz[(size_t)pt * 3 + 0];
        float yq = vxyz[(size_t)pt * 3 + 1];
        int x0 = (int)floorf(xq); x0 = min(max(x0, 0), W_ - 1);
        int x1 = min(x0 + 1, W_ - 1);
        int y0 = (int)floorf(yq); y0 = min(max(y0, 0), H_ - 1);
        int y1 = min(y0 + 1, H_ - 1);
        float x0f = (float)x0, x1f = (float)x1, y0f = (float)y0, y1f = (float)y1;
        float wa = (x1f - xq) * (y1f - yq);
        float wb = (x1f - xq) * (yq - y0f);
        float wc = (xq - x0f) * (y1f - yq);
        float wd = (xq - x0f) * (yq - y0f);

        int ia = y0 * W_ + x0, ib = y1 * W_ + x0, ic = y0 * W_ + x1, id = y1 * W_ + x1;
        const int* rb = rid + (size_t)b * S_;

        int ra = rb[ia], rbn = rb[ib], rc = rb[ic], rd = rb[id];
        uint2 Ra = *(const uint2*)(gc + (size_t)max(ra,  0) * C_);
        uint2 Rb = *(const uint2*)(gc + (size_t)max(rbn, 0) * C_);
        uint2 Rc = *(const uint2*)(gc + (size_t)max(rc,  0) * C_);
        uint2 Rd = *(const uint2*)(gc + (size_t)max(rd,  0) * C_);

        float A0,A1,A2,A3, B0,B1,B2,B3, C0,C1,C2,C3, D0,D1,D2,D3;
        bf2x(Ra.x, A0, A1); bf2x(Ra.y, A2, A3);
        bf2x(Rb.x, B0, B1); bf2x(Rb.y, B2, B3);
        bf2x(Rc.x, C0, C1); bf2x(Rc.y, C2, C3);
        bf2x(Rd.x, D0, D1); bf2x(Rd.y, D2, D3);

        bool oa = ra >= 0, ob = rbn >= 0, oc = rc >= 0, od = rd >= 0;
        f32x4 res;
        res[0] = wa * (oa ? A0 : cstv[0]) + wb * (ob ? B0 : cstv[0])
               + wc * (oc ? C0 : cstv[0]) + wd * (od ? D0 : cstv[0]);
        res[1] = wa * (oa ? A1 : cstv[1]) + wb * (ob ? B1 : cstv[1])
               + wc * (oc ? C1 : cstv[1]) + wd * (od ? D1 : cstv[1]);
        res[2] = wa * (oa ? A2 : cstv[2]) + wb * (ob ? B2 : cstv[2])
               + wc * (oc ? C2 : cstv[2]) + wd * (od ? D2 : cstv[2]);
        res[3] = wa * (oa ? A3 : cstv[3]) + wb * (ob ? B3 : cstv[3])
               + wc * (oc ? C3 : cstv[3]) + wd * (od ? D3 : cstv[3]);

        *(f32x4*)(out + (size_t)pt * C_ + ch) = res;
    }
}

extern "C" void kernel_launch(void* const* d_in, const int* in_sizes, int n_in,
                              void* d_out, int out_size, void* d_ws, size_t ws_size,
                              hipStream_t stream)
{
    const float* feat     = (const float*)d_in[1];
    const int*   indices  = (const int*)d_in[3];
    const int*   paddings = (const int*)d_in[4];
    const float* vxyz     = (const float*)d_in[5];
    const float* w_pn     = (const float*)d_in[6];
    const float* g1       = (const float*)d_in[7];
    const float* b1       = (const float*)d_in[8];
    const float* m1       = (const float*)d_in[9];
    const float* v1       = (const float*)d_in[10];
    const float* cw       = (const float*)d_in[11];
    const float* g2       = (const float*)d_in[12];
    const float* b2       = (const float*)d_in[13];
    const float* m2       = (const float*)d_in[14];
    const float* v2       = (const float*)d_in[15];

    // ws layout: grid_c 25.6MB | cnt 2MB | gcursor 16B | cur 2MB | rid 2MB |
    //            off_c 0.8MB | cnt_c 0.8MB | ptid 0.8MB | rank 0.8MB |
    //            cwb 8KB | wpb 4KB | o1v/scv/shv 3x256B
    char* p = (char*)d_ws;
    unsigned short* grid_c = (unsigned short*)p;  p += (size_t)NPT_ * C_ * 2;
    int* cnt   = (int*)p;  p += (size_t)NVOX_ * 4;
    int* gcur  = (int*)p;  p += 16;
    int* cur   = (int*)p;  p += (size_t)NVOX_ * 4;
    int* rid   = (int*)p;  p += (size_t)NVOX_ * 4;
    int* off_c = (int*)p;  p += (size_t)NPT_ * 4;
    int* cnt_c = (int*)p;  p += (size_t)NPT_ * 4;
    int* ptid  = (int*)p;  p += (size_t)NPT_ * 4;
    int* rank  = (int*)p;  p += (size_t)NPT_ * 4;
    unsigned short* cwb = (unsigned short*)p;  p += 8 * 64 * 8 * 2;
    unsigned short* wpb = (unsigned short*)p;  p += 4 * 64 * 8 * 2;
    float* o1v = (float*)p;  p += 64 * 4;
    float* scv = (float*)p;  p += 64 * 4;
    float* shv = (float*)p;

    // clear cnt (2MB) + gcursor (16B)
    k_clear<<<513, 256, 0, stream>>>(cnt);

    // NPT_/4/256 = 196 blocks
    k_hist<<<196, 256, 0, stream>>>(indices, paddings, cnt, rank);

    k_offsets<<<513, 256, 0, stream>>>(cnt, cur, rid, off_c, cnt_c, gcur,
        cw, w_pn, g1, b1, m1, v1, g2, b2, m2, v2,
        cwb, wpb, o1v, scv, shv);

    // 782 blocks: atomic-free scatter
    k_ptid<<<(NPT_ + 255) / 256, 256, 0, stream>>>(indices, paddings, cur, rank, ptid);

    // nocc <= NPT_: 12500 waves -> 3125 blocks; waves early-out past nocc
    k_redconv<<<3125, 256, 0, stream>>>(feat, ptid, off_c, cnt_c, gcur,
        wpb, o1v, cwb, scv, shv, grid_c);

    // NPT_/32 = 6250 waves -> 1563 blocks
    k_gather32<<<1563, 256, 0, stream>>>(grid_c, rid, vxyz, shv, (float*)d_out);
}